// Round 4
// baseline (268.337 us; speedup 1.0000x reference)
//
#include <hip/hip_runtime.h>
#include <hip/hip_bf16.h>

typedef __bf16 bf16x8 __attribute__((ext_vector_type(8)));
typedef float f32x4 __attribute__((ext_vector_type(4)));
typedef unsigned short ushortx8 __attribute__((ext_vector_type(8)));

#define N_TOTAL 262144
#define D 128
#define K_TOTAL 1024
#define BN 256
#define NBLK (N_TOTAL / BN)  // 1024
#define BIGF 256.0f
#define BTILE_BYTES 16384  // 64 centroids x 128 dims x 2 B

__device__ __forceinline__ unsigned short f2bf(float x) {
  union { float f; unsigned u; } c;
  c.f = x;
  unsigned u = c.u;
  u += 0x7fffu + ((u >> 16) & 1u);  // RNE
  return (unsigned short)(u >> 16);
}

__device__ __forceinline__ unsigned umax(unsigned a, unsigned b) {
  return a > b ? a : b;
}

// Kernel 1: means fp32 -> bf16, plus BIG - 0.5*||m||^2 per centroid.
__global__ void prep_means(const float* __restrict__ means,
                           unsigned short* __restrict__ mbf,
                           float* __restrict__ bigm2) {
  int k = blockIdx.x, t = threadIdx.x;  // 1024 blocks x 64 threads
  float a = means[k * D + t];
  float b = means[k * D + t + 64];
  mbf[k * D + t] = f2bf(a);
  mbf[k * D + t + 64] = f2bf(b);
  float s = a * a + b * b;
#pragma unroll
  for (int m = 32; m; m >>= 1) s += __shfl_down(s, m, 64);
  if (t == 0) bigm2[k] = BIGF - 0.5f * s;
}

__device__ __forceinline__ void gload_lds16(const void* g, void* l) {
  __builtin_amdgcn_global_load_lds(
      (const __attribute__((address_space(1))) unsigned int*)g,
      (__attribute__((address_space(3))) unsigned int*)l, 16, 0, 0);
}

// Kernel 2: 256 rows/block, 4 waves x 64 rows. A-fragments in registers,
// B double-buffered in swizzled LDS via global_load_lds, packed-key argmax,
// exact fp32 loss for the winners. 4 blocks/CU (LDS 38.4KB, VGPR<=128).
__global__ __launch_bounds__(256, 4) void kmeans_main(
    const float* __restrict__ X, const unsigned short* __restrict__ mbf,
    const float* __restrict__ bigm2, const float* __restrict__ means,
    float* __restrict__ partials) {
  __shared__ __attribute__((aligned(16))) char Bs[2][BTILE_BYTES];  // 32 KB dbuf
  __shared__ float m2s[K_TOTAL];                                    // 4 KB
  __shared__ int idxs[BN];
  __shared__ float wsum[4];

  const int t = threadIdx.x;
  const int l = t & 63;
  const int w = t >> 6;
  const int lr = l & 15;
  const int lhi = l >> 4;
  const long nbase = (long)blockIdx.x * BN;

  // ---- stage B tile ks=0 (pre-swizzled global source, linear LDS dest) ----
  {
    const char* src = (const char*)mbf;
#pragma unroll
    for (int j = 0; j < 4; ++j) {
      unsigned doff = (unsigned)(w * 4096 + j * 1024 + l * 16);
      unsigned soff = doff ^ (((doff >> 8) & 7u) << 4);
      gload_lds16(src + soff, Bs[0] + (w * 4096 + j * 1024));
    }
  }

  // ---- A fragments: 64 rows/wave, loaded once from global, bf16 in regs ----
  bf16x8 a[4][4];  // [row-sub][d-sub]
#pragma unroll
  for (int rs = 0; rs < 4; ++rs)
#pragma unroll
    for (int ds = 0; ds < 4; ++ds) {
      const float* ap =
          X + (nbase + w * 64 + rs * 16 + lr) * D + ds * 32 + lhi * 8;
      float4 v0 = *(const float4*)ap;
      float4 v1 = *(const float4*)(ap + 4);
      ushortx8 p;
      p[0] = f2bf(v0.x); p[1] = f2bf(v0.y); p[2] = f2bf(v0.z); p[3] = f2bf(v0.w);
      p[4] = f2bf(v1.x); p[5] = f2bf(v1.y); p[6] = f2bf(v1.z); p[7] = f2bf(v1.w);
      union { ushortx8 u; bf16x8 b; } cv;
      cv.u = p;
      a[rs][ds] = cv.b;
    }

  // ---- stage bigm2 into LDS ----
  {
    float4 v = ((const float4*)bigm2)[t];  // 256*4 = 1024
    *(float4*)(m2s + t * 4) = v;
  }

  // ---- per-lane swizzled in-row B offsets (kt goes into the imm) ----
  int roff[4];
#pragma unroll
  for (int ds = 0; ds < 4; ++ds)
    roff[ds] = lr * 256 + ((ds * 64 + lhi * 16) ^ ((lr & 7) << 4));

  unsigned bk[4][4];  // running packed keys per (rs, e)
#pragma unroll
  for (int rs = 0; rs < 4; ++rs)
#pragma unroll
    for (int e = 0; e < 4; ++e) bk[rs][e] = 0u;

  __syncthreads();

  int cur = 0;
#pragma unroll 2
  for (int ks = 0; ks < 16; ++ks) {
    // prefetch next B tile into the other buffer (completes by __syncthreads)
    if (ks < 15) {
      const char* src = (const char*)mbf + (ks + 1) * BTILE_BYTES;
      char* dstbase = Bs[cur ^ 1];
#pragma unroll
      for (int j = 0; j < 4; ++j) {
        unsigned doff = (unsigned)(w * 4096 + j * 1024 + l * 16);
        unsigned soff = doff ^ (((doff >> 8) & 7u) << 4);
        gload_lds16(src + soff, dstbase + (w * 4096 + j * 1024));
      }
    }

    const char* bp = Bs[cur];
    float bm[4];
#pragma unroll
    for (int kt = 0; kt < 4; ++kt) bm[kt] = m2s[ks * 64 + kt * 16 + lr];

    f32x4 acc[4][4];
    // ds = 0: C-init = BIG - 0.5||m||^2 (no explicit zero/sub pass)
#pragma unroll
    for (int kt = 0; kt < 4; ++kt) {
      bf16x8 b = *(const bf16x8*)(bp + kt * 4096 + roff[0]);
      f32x4 cinit = {bm[kt], bm[kt], bm[kt], bm[kt]};
#pragma unroll
      for (int rs = 0; rs < 4; ++rs)
        acc[rs][kt] =
            __builtin_amdgcn_mfma_f32_16x16x32_bf16(a[rs][0], b, cinit, 0, 0, 0);
    }
#pragma unroll
    for (int ds = 1; ds < 4; ++ds)
#pragma unroll
      for (int kt = 0; kt < 4; ++kt) {
        bf16x8 b = *(const bf16x8*)(bp + kt * 4096 + roff[ds]);
#pragma unroll
        for (int rs = 0; rs < 4; ++rs)
          acc[rs][kt] = __builtin_amdgcn_mfma_f32_16x16x32_bf16(
              a[rs][ds], b, acc[rs][kt], 0, 0, 0);
      }

    // ---- packed-key running argmax: tree max (v_max3_u32 fusable) ----
    {
      unsigned kb = (unsigned)(ks * 64) | (unsigned)lr;
#pragma unroll
      for (int rs = 0; rs < 4; ++rs)
#pragma unroll
        for (int e = 0; e < 4; ++e) {
          unsigned k0 = (__float_as_uint(acc[rs][0][e]) & 0xFFFFFC00u) | kb;
          unsigned k1 = (__float_as_uint(acc[rs][1][e]) & 0xFFFFFC00u) | (kb + 16u);
          unsigned k2 = (__float_as_uint(acc[rs][2][e]) & 0xFFFFFC00u) | (kb + 32u);
          unsigned k3 = (__float_as_uint(acc[rs][3][e]) & 0xFFFFFC00u) | (kb + 48u);
          bk[rs][e] = umax(umax(umax(k0, k1), umax(k2, k3)), bk[rs][e]);
        }
    }

    __syncthreads();
    cur ^= 1;
  }

  // ---- reduce keys across the 16 column-lanes; extract centroid idx ----
#pragma unroll
  for (int rs = 0; rs < 4; ++rs)
#pragma unroll
    for (int e = 0; e < 4; ++e) {
      unsigned k = bk[rs][e];
#pragma unroll
      for (int m = 1; m < 16; m <<= 1) {
        unsigned o = (unsigned)__shfl_xor((int)k, m, 64);
        k = k > o ? k : o;
      }
      if (lr == 0) idxs[w * 64 + rs * 16 + lhi * 4 + e] = (int)(k & 1023u);
    }
  __syncthreads();

  // ---- exact fp32 loss for assigned centroids (1 row per thread) ----
  {
    long n = nbase + t;
    int ai = idxs[t];
    const float4* xr = (const float4*)(X + n * D);
    const float4* mr = (const float4*)(means + (long)ai * D);
    float s = 0.f;
#pragma unroll 8
    for (int i = 0; i < 32; ++i) {
      float4 xv = xr[i];
      float4 mv = mr[i];
      float d0 = xv.x - mv.x, d1 = xv.y - mv.y;
      float d2 = xv.z - mv.z, d3 = xv.w - mv.w;
      s = fmaf(d0, d0, s);
      s = fmaf(d1, d1, s);
      s = fmaf(d2, d2, s);
      s = fmaf(d3, d3, s);
    }
#pragma unroll
    for (int m = 32; m; m >>= 1) s += __shfl_down(s, m, 64);
    if (l == 0) wsum[w] = s;
  }
  __syncthreads();
  if (t == 0) partials[blockIdx.x] = wsum[0] + wsum[1] + wsum[2] + wsum[3];
}

// Kernel 3: deterministic fixed-order final reduction (double accum).
__global__ void reduce_loss(const float* __restrict__ partials,
                            float* __restrict__ out) {
  __shared__ double ws[4];
  int t = threadIdx.x;
  double s = 0.0;
  for (int i = t; i < NBLK; i += 256) s += (double)partials[i];
#pragma unroll
  for (int m = 32; m; m >>= 1) s += __shfl_down(s, m, 64);
  if ((t & 63) == 0) ws[t >> 6] = s;
  __syncthreads();
  if (t == 0) out[0] = (float)(ws[0] + ws[1] + ws[2] + ws[3]);
}

extern "C" void kernel_launch(void* const* d_in, const int* in_sizes, int n_in,
                              void* d_out, int out_size, void* d_ws,
                              size_t ws_size, hipStream_t stream) {
  const float* X = (const float*)d_in[0];
  const float* means = (const float*)d_in[1];
  float* out = (float*)d_out;
  char* ws = (char*)d_ws;
  unsigned short* mbf = (unsigned short*)ws;        // 262144 B
  float* bigm2 = (float*)(ws + 262144);             // 4096 B
  float* partials = (float*)(ws + 262144 + 4096);   // 4096 B

  prep_means<<<K_TOTAL, 64, 0, stream>>>(means, mbf, bigm2);
  kmeans_main<<<NBLK, 256, 0, stream>>>(X, mbf, bigm2, means, partials);
  reduce_loss<<<1, 256, 0, stream>>>(partials, out);
}

// Round 5
// 194.197 us; speedup vs baseline: 1.3818x; 1.3818x over previous
//
#include <hip/hip_runtime.h>
#include <hip/hip_bf16.h>

typedef __bf16 bf16x8 __attribute__((ext_vector_type(8)));
typedef float f32x4 __attribute__((ext_vector_type(4)));
typedef unsigned short ushortx8 __attribute__((ext_vector_type(8)));

#define N_TOTAL 262144
#define D 128
#define K_TOTAL 1024
#define BN 256
#define NBLK (N_TOTAL / BN)  // 1024
#define BIGF 256.0f

__device__ __forceinline__ unsigned short f2bf(float x) {
  union { float f; unsigned u; } c;
  c.f = x;
  unsigned u = c.u;
  u += 0x7fffu + ((u >> 16) & 1u);  // RNE
  return (unsigned short)(u >> 16);
}

__device__ __forceinline__ unsigned umax(unsigned a, unsigned b) {
  return a > b ? a : b;
}

// Kernel 1: means fp32 -> bf16, plus BIG - 0.5*||m||^2 per centroid.
__global__ void prep_means(const float* __restrict__ means,
                           unsigned short* __restrict__ mbf,
                           float* __restrict__ bigm2) {
  int k = blockIdx.x, t = threadIdx.x;  // 1024 blocks x 64 threads
  float a = means[k * D + t];
  float b = means[k * D + t + 64];
  mbf[k * D + t] = f2bf(a);
  mbf[k * D + t + 64] = f2bf(b);
  float s = a * a + b * b;
#pragma unroll
  for (int m = 32; m; m >>= 1) s += __shfl_down(s, m, 64);
  if (t == 0) bigm2[k] = BIGF - 0.5f * s;
}

// Kernel 2: 256 rows/block, 4 waves x 64 rows. A-fragments in registers.
// B fragments read directly from global (codebook = 256KB, L1/L2-resident) —
// no LDS staging, no per-tile barriers. Depth-1 software pipeline with
// statically-indexed double fragment buffers. Packed-key argmax.
__global__ __launch_bounds__(256) void kmeans_main(
    const float* __restrict__ X, const unsigned short* __restrict__ mbf,
    const float* __restrict__ bigm2, const float* __restrict__ means,
    float* __restrict__ partials) {
  __shared__ float m2s[K_TOTAL];  // 4 KB
  __shared__ int idxs[BN];
  __shared__ float wsum[4];

  const int t = threadIdx.x;
  const int l = t & 63;
  const int w = t >> 6;
  const int lr = l & 15;
  const int lhi = l >> 4;
  const long nbase = (long)blockIdx.x * BN;

  // ---- A fragments: 64 rows/wave, loaded once from global, bf16 in regs ----
  bf16x8 a[4][4];  // [row-sub][d-sub]
#pragma unroll
  for (int rs = 0; rs < 4; ++rs)
#pragma unroll
    for (int ds = 0; ds < 4; ++ds) {
      const float* ap =
          X + (nbase + w * 64 + rs * 16 + lr) * D + ds * 32 + lhi * 8;
      float4 v0 = *(const float4*)ap;
      float4 v1 = *(const float4*)(ap + 4);
      ushortx8 p;
      p[0] = f2bf(v0.x); p[1] = f2bf(v0.y); p[2] = f2bf(v0.z); p[3] = f2bf(v0.w);
      p[4] = f2bf(v1.x); p[5] = f2bf(v1.y); p[6] = f2bf(v1.z); p[7] = f2bf(v1.w);
      union { ushortx8 u; bf16x8 b; } cv;
      cv.u = p;
      a[rs][ds] = cv.b;
    }

  // ---- stage bigm2 into LDS ----
  {
    float4 v = ((const float4*)bigm2)[t];  // 256*4 = 1024
    *(float4*)(m2s + t * 4) = v;
  }

  unsigned bk[4][4];  // running packed keys per (rs, e)
#pragma unroll
  for (int rs = 0; rs < 4; ++rs)
#pragma unroll
    for (int e = 0; e < 4; ++e) bk[rs][e] = 0u;

  __syncthreads();  // m2s visible

  // Per-lane codebook base: row = kk*16 + lr (kk = 16-centroid step, 0..63),
  // dims lhi*8..+8 -> byte offset (kk*16+lr)*256 + lhi*16.
  const char* bbase = (const char*)mbf + (lr * 256 + lhi * 16);

  bf16x8 bA[4], bB[4];

#define PF(BUF, KK)                                         \
  {                                                         \
    const char* p_ = bbase + (unsigned)(KK) * 4096u;        \
    BUF[0] = *(const bf16x8*)(p_);                          \
    BUF[1] = *(const bf16x8*)(p_ + 64);                     \
    BUF[2] = *(const bf16x8*)(p_ + 128);                    \
    BUF[3] = *(const bf16x8*)(p_ + 192);                    \
  }

#define COMPUTE(BUF, KK)                                                     \
  {                                                                          \
    float m2v_ = m2s[(KK) * 16 + lr];                                        \
    f32x4 ci_ = {m2v_, m2v_, m2v_, m2v_};                                    \
    unsigned kb_ = (unsigned)((KK) * 16) | (unsigned)lr;                     \
    _Pragma("unroll") for (int rs_ = 0; rs_ < 4; ++rs_) {                    \
      f32x4 acc_ = __builtin_amdgcn_mfma_f32_16x16x32_bf16(a[rs_][0], BUF[0],\
                                                           ci_, 0, 0, 0);    \
      acc_ = __builtin_amdgcn_mfma_f32_16x16x32_bf16(a[rs_][1], BUF[1], acc_,\
                                                     0, 0, 0);               \
      acc_ = __builtin_amdgcn_mfma_f32_16x16x32_bf16(a[rs_][2], BUF[2], acc_,\
                                                     0, 0, 0);               \
      acc_ = __builtin_amdgcn_mfma_f32_16x16x32_bf16(a[rs_][3], BUF[3], acc_,\
                                                     0, 0, 0);               \
      _Pragma("unroll") for (int e_ = 0; e_ < 4; ++e_) {                     \
        unsigned key_ =                                                      \
            (__float_as_uint(acc_[e_]) & 0xFFFFFC00u) | kb_;                 \
        bk[rs_][e_] = umax(bk[rs_][e_], key_);                               \
      }                                                                      \
    }                                                                        \
  }

  PF(bA, 0);
  for (int kq = 0; kq < 16; ++kq) {
    const int k0 = kq * 4;
    PF(bB, k0 + 1);
    COMPUTE(bA, k0 + 0);
    PF(bA, k0 + 2);
    COMPUTE(bB, k0 + 1);
    PF(bB, k0 + 3);
    COMPUTE(bA, k0 + 2);
    if (kq < 15) PF(bA, k0 + 4);
    COMPUTE(bB, k0 + 3);
  }
#undef PF
#undef COMPUTE

  // ---- reduce keys across the 16 column-lanes; extract centroid idx ----
#pragma unroll
  for (int rs = 0; rs < 4; ++rs)
#pragma unroll
    for (int e = 0; e < 4; ++e) {
      unsigned k = bk[rs][e];
#pragma unroll
      for (int m = 1; m < 16; m <<= 1) {
        unsigned o = (unsigned)__shfl_xor((int)k, m, 64);
        k = umax(k, o);
      }
      if (lr == 0) idxs[w * 64 + rs * 16 + lhi * 4 + e] = (int)(k & 1023u);
    }
  __syncthreads();

  // ---- exact fp32 loss for assigned centroids (1 row per thread) ----
  {
    long n = nbase + t;
    int ai = idxs[t];
    const float4* xr = (const float4*)(X + n * D);
    const float4* mr = (const float4*)(means + (long)ai * D);
    float s = 0.f;
#pragma unroll 8
    for (int i = 0; i < 32; ++i) {
      float4 xv = xr[i];
      float4 mv = mr[i];
      float d0 = xv.x - mv.x, d1 = xv.y - mv.y;
      float d2 = xv.z - mv.z, d3 = xv.w - mv.w;
      s = fmaf(d0, d0, s);
      s = fmaf(d1, d1, s);
      s = fmaf(d2, d2, s);
      s = fmaf(d3, d3, s);
    }
#pragma unroll
    for (int m = 32; m; m >>= 1) s += __shfl_down(s, m, 64);
    if (l == 0) wsum[w] = s;
  }
  __syncthreads();
  if (t == 0) partials[blockIdx.x] = wsum[0] + wsum[1] + wsum[2] + wsum[3];
}

// Kernel 3: deterministic fixed-order final reduction (double accum).
__global__ void reduce_loss(const float* __restrict__ partials,
                            float* __restrict__ out) {
  __shared__ double ws[4];
  int t = threadIdx.x;
  double s = 0.0;
  for (int i = t; i < NBLK; i += 256) s += (double)partials[i];
#pragma unroll
  for (int m = 32; m; m >>= 1) s += __shfl_down(s, m, 64);
  if ((t & 63) == 0) ws[t >> 6] = s;
  __syncthreads();
  if (t == 0) out[0] = (float)(ws[0] + ws[1] + ws[2] + ws[3]);
}

extern "C" void kernel_launch(void* const* d_in, const int* in_sizes, int n_in,
                              void* d_out, int out_size, void* d_ws,
                              size_t ws_size, hipStream_t stream) {
  const float* X = (const float*)d_in[0];
  const float* means = (const float*)d_in[1];
  float* out = (float*)d_out;
  char* ws = (char*)d_ws;
  unsigned short* mbf = (unsigned short*)ws;        // 262144 B
  float* bigm2 = (float*)(ws + 262144);             // 4096 B
  float* partials = (float*)(ws + 262144 + 4096);   // 4096 B

  prep_means<<<K_TOTAL, 64, 0, stream>>>(means, mbf, bigm2);
  kmeans_main<<<NBLK, 256, 0, stream>>>(X, mbf, bigm2, means, partials);
  reduce_loss<<<1, 256, 0, stream>>>(partials, out);
}

// Round 7
// 168.419 us; speedup vs baseline: 1.5933x; 1.1531x over previous
//
#include <hip/hip_runtime.h>
#include <hip/hip_bf16.h>

typedef __bf16 bf16x8 __attribute__((ext_vector_type(8)));
typedef float f32x4 __attribute__((ext_vector_type(4)));
typedef unsigned short ushortx8 __attribute__((ext_vector_type(8)));

#define N_TOTAL 262144
#define D 128
#define K_TOTAL 1024
#define BN 256
#define NBLK (N_TOTAL / BN)  // 1024
#define BIGF 256.0f
// Combined tile record: 64 centroids x 128 d bf16 (16384 B) + 64 m2 floats (256 B)
#define TREC 16640
#define NT 16

__device__ __forceinline__ unsigned short f2bf(float x) {
  union { float f; unsigned u; } c;
  c.f = x;
  unsigned u = c.u;
  u += 0x7fffu + ((u >> 16) & 1u);  // RNE
  return (unsigned short)(u >> 16);
}

__device__ __forceinline__ unsigned umax(unsigned a, unsigned b) {
  return a > b ? a : b;
}

// Kernel 1: pack codebook into per-tile records: bf16 B + (BIG - 0.5||m||^2).
__global__ void prep_means(const float* __restrict__ means,
                           char* __restrict__ mtiles) {
  int k = blockIdx.x, t = threadIdx.x;  // 1024 blocks x 64 threads
  float a = means[k * D + t];
  float b = means[k * D + t + 64];
  int ts = k >> 6, j = k & 63;
  unsigned short* brow = (unsigned short*)(mtiles + ts * TREC + j * 256);
  brow[t] = f2bf(a);
  brow[t + 64] = f2bf(b);
  float s = a * a + b * b;
#pragma unroll
  for (int m = 32; m; m >>= 1) s += __shfl_down(s, m, 64);
  if (t == 0)
    *(float*)(mtiles + ts * TREC + 16384 + j * 4) = BIGF - 0.5f * s;
}

__device__ __forceinline__ void gload_lds16(const void* g, void* l) {
  __builtin_amdgcn_global_load_lds(
      (const __attribute__((address_space(1))) unsigned int*)g,
      (__attribute__((address_space(3))) unsigned int*)l, 16, 0, 0);
}
__device__ __forceinline__ void gload_lds4(const void* g, void* l) {
  __builtin_amdgcn_global_load_lds(
      (const __attribute__((address_space(1))) unsigned int*)g,
      (__attribute__((address_space(3))) unsigned int*)l, 4, 0, 0);
}

// Kernel 2: 256 rows/block, 4 waves x 64 rows. A in registers; B tiles
// streamed through a 3-buffer LDS rotation with depth-2 prefetch and
// COUNTED vmcnt (never 0 in-loop) + raw s_barrier (T3+T4). Packed-key argmax.
__global__ __launch_bounds__(256) void kmeans_main(
    const float* __restrict__ X, const char* __restrict__ mtiles,
    const float* __restrict__ means, float* __restrict__ partials) {
  __shared__ __attribute__((aligned(16))) char Bs[3 * TREC];  // 48.75 KB
  __shared__ int idxs[BN];
  __shared__ float wsum[4];

  const int t = threadIdx.x;
  const int l = t & 63;
  const int w = t >> 6;
  const int lr = l & 15;
  const int lhi = l >> 4;
  const long nbase = (long)blockIdx.x * BN;

  // ---- A fragments: 64 rows/wave, loaded once from global, bf16 in regs ----
  bf16x8 a[4][4];  // [row-sub][d-sub]
#pragma unroll
  for (int rs = 0; rs < 4; ++rs)
#pragma unroll
    for (int ds = 0; ds < 4; ++ds) {
      const float* ap =
          X + (nbase + w * 64 + rs * 16 + lr) * D + ds * 32 + lhi * 8;
      float4 v0 = *(const float4*)ap;
      float4 v1 = *(const float4*)(ap + 4);
      ushortx8 p;
      p[0] = f2bf(v0.x); p[1] = f2bf(v0.y); p[2] = f2bf(v0.z); p[3] = f2bf(v0.w);
      p[4] = f2bf(v1.x); p[5] = f2bf(v1.y); p[6] = f2bf(v1.z); p[7] = f2bf(v1.w);
      union { ushortx8 u; bf16x8 b; } cv;
      cv.u = p;
      a[rs][ds] = cv.b;
    }

  // ---- per-lane swizzled in-row B offsets ----
  int roff[4];
#pragma unroll
  for (int ds = 0; ds < 4; ++ds)
    roff[ds] = lr * 256 + ((ds * 64 + lhi * 16) ^ ((lr & 7) << 4));

  unsigned bk[4][4];  // running packed keys per (rs, e)
#pragma unroll
  for (int rs = 0; rs < 4; ++rs)
#pragma unroll
    for (int e = 0; e < 4; ++e) bk[rs][e] = 0u;

  // Drain A-loads so in-loop vmcnt counting sees only tile prefetches.
  __syncthreads();

  // ---- prologue: prefetch tiles 0 and 1 (5 loads/wave each, uniform) ----
#pragma unroll
  for (int pt = 0; pt < 2; ++pt) {
    const char* src = mtiles + pt * TREC;
    char* dst = Bs + pt * TREC;
#pragma unroll
    for (int j = 0; j < 4; ++j) {
      unsigned doff = (unsigned)(w * 4096 + j * 1024 + l * 16);
      unsigned soff = doff ^ (((doff >> 8) & 7u) << 4);
      gload_lds16(src + soff, dst + (w * 4096 + j * 1024));
    }
    // per-lane SOURCE (lane l fetches m2[l]); LDS dest = base + l*4
    gload_lds4(src + 16384 + l * 4, dst + 16384);
  }

  int cb = 0;  // compute buffer index (t % 3)
  int pb = 2;  // prefetch buffer index ((t+2) % 3)

#define COMPUTE_TILE(TT, BP)                                                 \
  {                                                                          \
    unsigned kb_ = (unsigned)((TT) * 64) | (unsigned)lr;                     \
    _Pragma("unroll") for (int kt_ = 0; kt_ < 4; ++kt_) {                    \
      float m2v_ = *(const float*)((BP) + 16384 + (kt_ * 16 + lr) * 4);      \
      f32x4 ci_ = {m2v_, m2v_, m2v_, m2v_};                                  \
      bf16x8 b0_ = *(const bf16x8*)((BP) + kt_ * 4096 + roff[0]);            \
      bf16x8 b1_ = *(const bf16x8*)((BP) + kt_ * 4096 + roff[1]);            \
      bf16x8 b2_ = *(const bf16x8*)((BP) + kt_ * 4096 + roff[2]);            \
      bf16x8 b3_ = *(const bf16x8*)((BP) + kt_ * 4096 + roff[3]);            \
      unsigned kk_ = kb_ + (unsigned)(kt_ * 16);                             \
      _Pragma("unroll") for (int rs_ = 0; rs_ < 4; ++rs_) {                  \
        f32x4 acc_ = __builtin_amdgcn_mfma_f32_16x16x32_bf16(a[rs_][0], b0_, \
                                                             ci_, 0, 0, 0);  \
        acc_ = __builtin_amdgcn_mfma_f32_16x16x32_bf16(a[rs_][1], b1_, acc_, \
                                                       0, 0, 0);             \
        acc_ = __builtin_amdgcn_mfma_f32_16x16x32_bf16(a[rs_][2], b2_, acc_, \
                                                       0, 0, 0);             \
        acc_ = __builtin_amdgcn_mfma_f32_16x16x32_bf16(a[rs_][3], b3_, acc_, \
                                                       0, 0, 0);             \
        _Pragma("unroll") for (int e_ = 0; e_ < 4; ++e_) {                   \
          unsigned key_ = (__float_as_uint(acc_[e_]) & 0xFFFFFC00u) | kk_;   \
          bk[rs_][e_] = umax(bk[rs_][e_], key_);                             \
        }                                                                    \
      }                                                                      \
    }                                                                        \
  }

  for (int tt = 0; tt < NT - 1; ++tt) {
    // steady state: 10 loads outstanding (tiles tt, tt+1); wait tile tt's 5.
    asm volatile("s_waitcnt vmcnt(5)" ::: "memory");
    __builtin_amdgcn_s_barrier();
    if (tt < NT - 2) {
      const char* src = mtiles + (tt + 2) * TREC;
      char* dst = Bs + pb * TREC;
#pragma unroll
      for (int j = 0; j < 4; ++j) {
        unsigned doff = (unsigned)(w * 4096 + j * 1024 + l * 16);
        unsigned soff = doff ^ (((doff >> 8) & 7u) << 4);
        gload_lds16(src + soff, dst + (w * 4096 + j * 1024));
      }
      gload_lds4(src + 16384 + l * 4, dst + 16384);
    }
    const char* bp = Bs + cb * TREC;
    COMPUTE_TILE(tt, bp);
    cb = (cb == 2) ? 0 : cb + 1;
    pb = (pb == 2) ? 0 : pb + 1;
  }
  // epilogue tile NT-1: drain remaining loads.
  asm volatile("s_waitcnt vmcnt(0)" ::: "memory");
  __builtin_amdgcn_s_barrier();
  {
    const char* bp = Bs + cb * TREC;
    COMPUTE_TILE(NT - 1, bp);
  }
#undef COMPUTE_TILE

  // ---- reduce keys across the 16 column-lanes; extract centroid idx ----
#pragma unroll
  for (int rs = 0; rs < 4; ++rs)
#pragma unroll
    for (int e = 0; e < 4; ++e) {
      unsigned k = bk[rs][e];
#pragma unroll
      for (int m = 1; m < 16; m <<= 1) {
        unsigned o = (unsigned)__shfl_xor((int)k, m, 64);
        k = umax(k, o);
      }
      if (lr == 0) idxs[w * 64 + rs * 16 + lhi * 4 + e] = (int)(k & 1023u);
    }
  __syncthreads();

  // ---- exact fp32 loss for assigned centroids (1 row per thread) ----
  {
    long n = nbase + t;
    int ai = idxs[t];
    const float4* xr = (const float4*)(X + n * D);
    const float4* mr = (const float4*)(means + (long)ai * D);
    float s = 0.f;
#pragma unroll 8
    for (int i = 0; i < 32; ++i) {
      float4 xv = xr[i];
      float4 mv = mr[i];
      float d0 = xv.x - mv.x, d1 = xv.y - mv.y;
      float d2 = xv.z - mv.z, d3 = xv.w - mv.w;
      s = fmaf(d0, d0, s);
      s = fmaf(d1, d1, s);
      s = fmaf(d2, d2, s);
      s = fmaf(d3, d3, s);
    }
#pragma unroll
    for (int m = 32; m; m >>= 1) s += __shfl_down(s, m, 64);
    if (l == 0) wsum[w] = s;
  }
  __syncthreads();
  if (t == 0) partials[blockIdx.x] = wsum[0] + wsum[1] + wsum[2] + wsum[3];
}

// Kernel 3: deterministic fixed-order final reduction (double accum).
__global__ void reduce_loss(const float* __restrict__ partials,
                            float* __restrict__ out) {
  __shared__ double ws[4];
  int t = threadIdx.x;
  double s = 0.0;
  for (int i = t; i < NBLK; i += 256) s += (double)partials[i];
#pragma unroll
  for (int m = 32; m; m >>= 1) s += __shfl_down(s, m, 64);
  if ((t & 63) == 0) ws[t >> 6] = s;
  __syncthreads();
  if (t == 0) out[0] = (float)(ws[0] + ws[1] + ws[2] + ws[3]);
}

extern "C" void kernel_launch(void* const* d_in, const int* in_sizes, int n_in,
                              void* d_out, int out_size, void* d_ws,
                              size_t ws_size, hipStream_t stream) {
  const float* X = (const float*)d_in[0];
  const float* means = (const float*)d_in[1];
  float* out = (float*)d_out;
  char* ws = (char*)d_ws;
  char* mtiles = ws;                              // 16 * 16640 = 266240 B
  float* partials = (float*)(ws + NT * TREC);     // 4096 B

  prep_means<<<K_TOTAL, 64, 0, stream>>>(means, mtiles);
  kmeans_main<<<NBLK, 256, 0, stream>>>(X, mtiles, means, partials);
  reduce_loss<<<1, 256, 0, stream>>>(partials, out);
}

// Round 8
// 106.273 us; speedup vs baseline: 2.5250x; 1.5848x over previous
//
#include <hip/hip_runtime.h>
#include <hip/hip_bf16.h>

typedef __bf16 bf16x8 __attribute__((ext_vector_type(8)));
typedef float f32x4 __attribute__((ext_vector_type(4)));
typedef unsigned short ushortx8 __attribute__((ext_vector_type(8)));

#define N_TOTAL 262144
#define D 128
#define K_TOTAL 1024
#define BN 256
#define NBLK (N_TOTAL / BN)  // 1024
#define BIGF 256.0f

__device__ __forceinline__ unsigned short f2bf(float x) {
  union { float f; unsigned u; } c;
  c.f = x;
  unsigned u = c.u;
  u += 0x7fffu + ((u >> 16) & 1u);  // RNE
  return (unsigned short)(u >> 16);
}

__device__ __forceinline__ unsigned umax(unsigned a, unsigned b) {
  return a > b ? a : b;
}

// Kernel 1: means fp32 -> bf16, plus BIG - 0.5*||m||^2 per centroid.
__global__ void prep_means(const float* __restrict__ means,
                           unsigned short* __restrict__ mbf,
                           float* __restrict__ bigm2) {
  int k = blockIdx.x, t = threadIdx.x;  // 1024 blocks x 64 threads
  float a = means[k * D + t];
  float b = means[k * D + t + 64];
  mbf[k * D + t] = f2bf(a);
  mbf[k * D + t + 64] = f2bf(b);
  float s = a * a + b * b;
#pragma unroll
  for (int m = 32; m; m >>= 1) s += __shfl_down(s, m, 64);
  if (t == 0) bigm2[k] = BIGF - 0.5f * s;
}

// Kernel 2: 256 rows/block, 4 waves x 64 rows. A in registers. B tiles
// staged global->REG (issued before compute) -> ds_write AFTER compute
// (T14 async split: HBM latency hides under MFMA; barrier drains only LDS).
// Per-block tile rotation desyncs L2 bursts. Packed-key tree argmax.
__global__ __launch_bounds__(256, 2) void kmeans_main(
    const float* __restrict__ X, const unsigned short* __restrict__ mbf,
    const float* __restrict__ bigm2, const float* __restrict__ means,
    float* __restrict__ partials) {
  __shared__ __attribute__((aligned(16))) char Bs[2][16384];  // 32 KB dbuf
  __shared__ float m2s[K_TOTAL];                              // 4 KB
  __shared__ int idxs[BN];
  __shared__ float wsum[4];

  const int t = threadIdx.x;
  const int l = t & 63;
  const int w = t >> 6;
  const int lr = l & 15;
  const int lhi = l >> 4;
  const int rot = blockIdx.x & 15;
  const long nbase = (long)blockIdx.x * BN;

  // ---- A fragments: 64 rows/wave, loaded once from global, bf16 in regs ----
  bf16x8 a[4][4];  // [row-sub][d-sub]
#pragma unroll
  for (int rs = 0; rs < 4; ++rs)
#pragma unroll
    for (int ds = 0; ds < 4; ++ds) {
      const float* ap =
          X + (nbase + w * 64 + rs * 16 + lr) * D + ds * 32 + lhi * 8;
      float4 v0 = *(const float4*)ap;
      float4 v1 = *(const float4*)(ap + 4);
      ushortx8 p;
      p[0] = f2bf(v0.x); p[1] = f2bf(v0.y); p[2] = f2bf(v0.z); p[3] = f2bf(v0.w);
      p[4] = f2bf(v1.x); p[5] = f2bf(v1.y); p[6] = f2bf(v1.z); p[7] = f2bf(v1.w);
      union { ushortx8 u; bf16x8 b; } cv;
      cv.u = p;
      a[rs][ds] = cv.b;
    }

  // ---- stage bigm2 into LDS (once, all 16 tiles) ----
  {
    float4 v = ((const float4*)bigm2)[t];  // 256*4 = 1024
    *(float4*)(m2s + t * 4) = v;
  }

  // ---- read-side swizzled in-row B offsets ----
  int roff[4];
#pragma unroll
  for (int ds = 0; ds < 4; ++ds)
    roff[ds] = lr * 256 + ((ds * 64 + lhi * 16) ^ ((lr & 7) << 4));

  // ---- write-side staging offsets: g(j) = j*4096 + t*16; same XOR ----
  const unsigned lbase = (unsigned)(t * 16) ^ (((unsigned)(t >> 4) & 7u) << 4);

  unsigned bk[4][4];  // running packed keys per (rs, e)
#pragma unroll
  for (int rs = 0; rs < 4; ++rs)
#pragma unroll
    for (int e = 0; e < 4; ++e) bk[rs][e] = 0u;

  // ---- prologue: stage tile `rot` into Bs[0] via regs ----
  {
    const char* src = (const char*)mbf + rot * 16384;
    uint4 s0 = *(const uint4*)(src + 0 * 4096 + t * 16);
    uint4 s1 = *(const uint4*)(src + 1 * 4096 + t * 16);
    uint4 s2 = *(const uint4*)(src + 2 * 4096 + t * 16);
    uint4 s3 = *(const uint4*)(src + 3 * 4096 + t * 16);
    *(uint4*)(Bs[0] + 0 * 4096 + lbase) = s0;
    *(uint4*)(Bs[0] + 1 * 4096 + lbase) = s1;
    *(uint4*)(Bs[0] + 2 * 4096 + lbase) = s2;
    *(uint4*)(Bs[0] + 3 * 4096 + lbase) = s3;
  }
  __syncthreads();

#define COMPUTE_TILE(TID, BP)                                                \
  {                                                                          \
    unsigned kb_ = (unsigned)((TID) * 64) | (unsigned)lr;                    \
    _Pragma("unroll") for (int kt_ = 0; kt_ < 4; ++kt_) {                    \
      float m2v_ = m2s[(TID) * 64 + kt_ * 16 + lr];                          \
      f32x4 ci_ = {m2v_, m2v_, m2v_, m2v_};                                  \
      bf16x8 b0_ = *(const bf16x8*)((BP) + kt_ * 4096 + roff[0]);            \
      bf16x8 b1_ = *(const bf16x8*)((BP) + kt_ * 4096 + roff[1]);            \
      bf16x8 b2_ = *(const bf16x8*)((BP) + kt_ * 4096 + roff[2]);            \
      bf16x8 b3_ = *(const bf16x8*)((BP) + kt_ * 4096 + roff[3]);            \
      unsigned kk_ = kb_ + (unsigned)(kt_ * 16);                             \
      _Pragma("unroll") for (int rs_ = 0; rs_ < 4; ++rs_) {                  \
        f32x4 acc_ = __builtin_amdgcn_mfma_f32_16x16x32_bf16(a[rs_][0], b0_, \
                                                             ci_, 0, 0, 0);  \
        acc_ = __builtin_amdgcn_mfma_f32_16x16x32_bf16(a[rs_][1], b1_, acc_, \
                                                       0, 0, 0);             \
        acc_ = __builtin_amdgcn_mfma_f32_16x16x32_bf16(a[rs_][2], b2_, acc_, \
                                                       0, 0, 0);             \
        acc_ = __builtin_amdgcn_mfma_f32_16x16x32_bf16(a[rs_][3], b3_, acc_, \
                                                       0, 0, 0);             \
        unsigned k0_ = (__float_as_uint(acc_[0]) & 0xFFFFFC00u) | kk_;       \
        unsigned k1_ = (__float_as_uint(acc_[1]) & 0xFFFFFC00u) | kk_;       \
        unsigned k2_ = (__float_as_uint(acc_[2]) & 0xFFFFFC00u) | kk_;       \
        unsigned k3_ = (__float_as_uint(acc_[3]) & 0xFFFFFC00u) | kk_;       \
        bk[rs_][0] = umax(bk[rs_][0], k0_);                                  \
        bk[rs_][1] = umax(bk[rs_][1], k1_);                                  \
        bk[rs_][2] = umax(bk[rs_][2], k2_);                                  \
        bk[rs_][3] = umax(bk[rs_][3], k3_);                                  \
      }                                                                      \
    }                                                                        \
  }

  int cur = 0;
  for (int ks = 0; ks < 16; ++ks) {
    const int tid = (rot + ks) & 15;
    uint4 s0, s1, s2, s3;
    if (ks < 15) {
      // issue next tile's global loads EARLY (latency hides under compute)
      const char* src = (const char*)mbf + (((rot + ks + 1) & 15) * 16384);
      s0 = *(const uint4*)(src + 0 * 4096 + t * 16);
      s1 = *(const uint4*)(src + 1 * 4096 + t * 16);
      s2 = *(const uint4*)(src + 2 * 4096 + t * 16);
      s3 = *(const uint4*)(src + 3 * 4096 + t * 16);
    }
    const char* bp = Bs[cur];
    COMPUTE_TILE(tid, bp);
    if (ks < 15) {
      // write the (by-now landed) regs into the other buffer
      char* dst = Bs[cur ^ 1];
      *(uint4*)(dst + 0 * 4096 + lbase) = s0;
      *(uint4*)(dst + 1 * 4096 + lbase) = s1;
      *(uint4*)(dst + 2 * 4096 + lbase) = s2;
      *(uint4*)(dst + 3 * 4096 + lbase) = s3;
    }
    __syncthreads();
    cur ^= 1;
  }
#undef COMPUTE_TILE

  // ---- reduce keys across the 16 column-lanes; extract centroid idx ----
#pragma unroll
  for (int rs = 0; rs < 4; ++rs)
#pragma unroll
    for (int e = 0; e < 4; ++e) {
      unsigned k = bk[rs][e];
#pragma unroll
      for (int m = 1; m < 16; m <<= 1) {
        unsigned o = (unsigned)__shfl_xor((int)k, m, 64);
        k = umax(k, o);
      }
      if (lr == 0) idxs[w * 64 + rs * 16 + lhi * 4 + e] = (int)(k & 1023u);
    }
  __syncthreads();

  // ---- exact fp32 loss for assigned centroids (1 row per thread) ----
  {
    long n = nbase + t;
    int ai = idxs[t];
    const float4* xr = (const float4*)(X + n * D);
    const float4* mr = (const float4*)(means + (long)ai * D);
    float s = 0.f;
#pragma unroll 8
    for (int i = 0; i < 32; ++i) {
      float4 xv = xr[i];
      float4 mv = mr[i];
      float d0 = xv.x - mv.x, d1 = xv.y - mv.y;
      float d2 = xv.z - mv.z, d3 = xv.w - mv.w;
      s = fmaf(d0, d0, s);
      s = fmaf(d1, d1, s);
      s = fmaf(d2, d2, s);
      s = fmaf(d3, d3, s);
    }
#pragma unroll
    for (int m = 32; m; m >>= 1) s += __shfl_down(s, m, 64);
    if (l == 0) wsum[w] = s;
  }
  __syncthreads();
  if (t == 0) partials[blockIdx.x] = wsum[0] + wsum[1] + wsum[2] + wsum[3];
}

// Kernel 3: deterministic fixed-order final reduction (double accum).
__global__ void reduce_loss(const float* __restrict__ partials,
                            float* __restrict__ out) {
  __shared__ double ws[4];
  int t = threadIdx.x;
  double s = 0.0;
  for (int i = t; i < NBLK; i += 256) s += (double)partials[i];
#pragma unroll
  for (int m = 32; m; m >>= 1) s += __shfl_down(s, m, 64);
  if ((t & 63) == 0) ws[t >> 6] = s;
  __syncthreads();
  if (t == 0) out[0] = (float)(ws[0] + ws[1] + ws[2] + ws[3]);
}

extern "C" void kernel_launch(void* const* d_in, const int* in_sizes, int n_in,
                              void* d_out, int out_size, void* d_ws,
                              size_t ws_size, hipStream_t stream) {
  const float* X = (const float*)d_in[0];
  const float* means = (const float*)d_in[1];
  float* out = (float*)d_out;
  char* ws = (char*)d_ws;
  unsigned short* mbf = (unsigned short*)ws;        // 262144 B
  float* bigm2 = (float*)(ws + 262144);             // 4096 B
  float* partials = (float*)(ws + 262144 + 4096);   // 4096 B

  prep_means<<<K_TOTAL, 64, 0, stream>>>(means, mbf, bigm2);
  kmeans_main<<<NBLK, 256, 0, stream>>>(X, mbf, bigm2, means, partials);
  reduce_loss<<<1, 256, 0, stream>>>(partials, out);
}

// Round 9
// 104.658 us; speedup vs baseline: 2.5639x; 1.0154x over previous
//
#include <hip/hip_runtime.h>
#include <hip/hip_fp8.h>

typedef float f32x4 __attribute__((ext_vector_type(4)));

#define N_TOTAL 262144
#define D 128
#define K_TOTAL 1024
#define BN 256
#define NBLK (N_TOTAL / BN)  // 1024
#define BIGF 256.0f
#define TILEB 8192  // 64 centroids x 128 dims x 1 B (fp8)

__device__ __forceinline__ unsigned f2fp8(float x) {
  return (unsigned)__hip_fp8_e4m3(x).__x;
}

__device__ __forceinline__ unsigned umax(unsigned a, unsigned b) {
  return a > b ? a : b;
}

// Kernel 1: codebook fp32 -> fp8 e4m3 (tile-major row layout) + BIG - 0.5||m||^2.
__global__ void prep_means(const float* __restrict__ means,
                           unsigned char* __restrict__ mbf8,
                           float* __restrict__ bigm2) {
  int k = blockIdx.x, t = threadIdx.x;  // 1024 blocks x 64 threads
  float a = means[k * D + 2 * t];
  float b = means[k * D + 2 * t + 1];
  int ts = k >> 6, j = k & 63;
  unsigned short pk = (unsigned short)(f2fp8(a) | (f2fp8(b) << 8));
  *(unsigned short*)(mbf8 + ts * TILEB + j * 128 + 2 * t) = pk;
  float s = a * a + b * b;
#pragma unroll
  for (int m = 32; m; m >>= 1) s += __shfl_down(s, m, 64);
  if (t == 0) bigm2[k] = BIGF - 0.5f * s;
}

// Kernel 2: 256 rows/block, 4 waves x 64 rows. A in registers (fp8). B tiles
// (fp8, 8KB) staged global->REG early -> swizzled ds_write after compute
// (T14). No waves-per-EU cap: occupancy is resource-driven (LDS ~21.5KB,
// VGPR ~85 -> 4 blocks/CU). Packed-key argmax; exact fp32 loss for winners.
__global__ __launch_bounds__(256) void kmeans_main(
    const float* __restrict__ X, const unsigned char* __restrict__ mbf8,
    const float* __restrict__ bigm2, const float* __restrict__ means,
    float* __restrict__ partials) {
  __shared__ __attribute__((aligned(16))) char Bs[2][TILEB];  // 16 KB dbuf
  __shared__ float m2s[K_TOTAL];                              // 4 KB
  __shared__ int idxs[BN];
  __shared__ float wsum[4];

  const int t = threadIdx.x;
  const int l = t & 63;
  const int w = t >> 6;
  const int lr = l & 15;
  const int lhi = l >> 4;
  const int rot = blockIdx.x & 15;
  const long nbase = (long)blockIdx.x * BN;

  // ---- A fragments: 64 rows/wave, fp32 -> fp8, 8 bytes (1 reg-pair) each ----
  long a[4][4];  // [row-sub][d-sub]
#pragma unroll
  for (int rs = 0; rs < 4; ++rs)
#pragma unroll
    for (int ds = 0; ds < 4; ++ds) {
      const float* ap =
          X + (nbase + w * 64 + rs * 16 + lr) * D + ds * 32 + lhi * 8;
      float4 v0 = *(const float4*)ap;
      float4 v1 = *(const float4*)(ap + 4);
      unsigned lo = f2fp8(v0.x) | (f2fp8(v0.y) << 8) | (f2fp8(v0.z) << 16) |
                    (f2fp8(v0.w) << 24);
      unsigned hi = f2fp8(v1.x) | (f2fp8(v1.y) << 8) | (f2fp8(v1.z) << 16) |
                    (f2fp8(v1.w) << 24);
      a[rs][ds] = (long)(((unsigned long long)hi << 32) | lo);
    }

  // ---- stage bigm2 into LDS (once, all 16 tiles) ----
  {
    float4 v = ((const float4*)bigm2)[t];  // 256*4 = 1024
    *(float4*)(m2s + t * 4) = v;
  }

  // ---- read-side swizzled fragment offsets ----
  // frag(row, ds) at row*128 + ((ds*4 + lhi) ^ ((row&7)<<1)) * 8 ; row=kt*16+lr
  int roff[4];
#pragma unroll
  for (int ds = 0; ds < 4; ++ds)
    roff[ds] = lr * 128 + ((((ds * 4 + lhi) ^ ((lr & 7) << 1))) << 3);

  // ---- write-side staging map: thread t owns linear bytes [t*32, t*32+32) ----
  const int srow = t >> 2;                              // 0..63
  const int sq0 = (t & 3) * 4;                          // slot base 0..12
  const unsigned sswz = (unsigned)((srow & 7) << 1);
  const unsigned wdst0 = (unsigned)(srow * 128 + (((unsigned)sq0 ^ sswz) << 3));
  const unsigned wdst1 =
      (unsigned)(srow * 128 + ((((unsigned)sq0 + 2u) ^ sswz) << 3));

  unsigned bk[4][4];  // running packed keys per (rs, e)
#pragma unroll
  for (int rs = 0; rs < 4; ++rs)
#pragma unroll
    for (int e = 0; e < 4; ++e) bk[rs][e] = 0u;

  // ---- prologue: stage tile `rot` into Bs[0] ----
  {
    const char* src = (const char*)mbf8 + rot * TILEB;
    uint4 s0 = *(const uint4*)(src + t * 32);
    uint4 s1 = *(const uint4*)(src + t * 32 + 16);
    *(uint4*)(Bs[0] + wdst0) = s0;
    *(uint4*)(Bs[0] + wdst1) = s1;
  }
  __syncthreads();

#define COMPUTE_TILE(TID, BP)                                                  \
  {                                                                            \
    _Pragma("unroll") for (int kt_ = 0; kt_ < 4; ++kt_) {                      \
      float m2v_ = m2s[(TID) * 64 + kt_ * 16 + lr];                            \
      f32x4 ci_ = {m2v_, m2v_, m2v_, m2v_};                                    \
      long b0_ = *(const long*)((BP) + kt_ * 2048 + roff[0]);                  \
      long b1_ = *(const long*)((BP) + kt_ * 2048 + roff[1]);                  \
      long b2_ = *(const long*)((BP) + kt_ * 2048 + roff[2]);                  \
      long b3_ = *(const long*)((BP) + kt_ * 2048 + roff[3]);                  \
      unsigned kk_ = (unsigned)((TID) * 64 + kt_ * 16) | (unsigned)lr;         \
      _Pragma("unroll") for (int rs_ = 0; rs_ < 4; ++rs_) {                    \
        f32x4 acc_ = __builtin_amdgcn_mfma_f32_16x16x32_fp8_fp8(               \
            a[rs_][0], b0_, ci_, 0, 0, 0);                                     \
        acc_ = __builtin_amdgcn_mfma_f32_16x16x32_fp8_fp8(a[rs_][1], b1_,      \
                                                          acc_, 0, 0, 0);      \
        acc_ = __builtin_amdgcn_mfma_f32_16x16x32_fp8_fp8(a[rs_][2], b2_,      \
                                                          acc_, 0, 0, 0);      \
        acc_ = __builtin_amdgcn_mfma_f32_16x16x32_fp8_fp8(a[rs_][3], b3_,      \
                                                          acc_, 0, 0, 0);      \
        unsigned k0_ = (__float_as_uint(acc_[0]) & 0xFFFFFC00u) | kk_;         \
        unsigned k1_ = (__float_as_uint(acc_[1]) & 0xFFFFFC00u) | kk_;         \
        unsigned k2_ = (__float_as_uint(acc_[2]) & 0xFFFFFC00u) | kk_;         \
        unsigned k3_ = (__float_as_uint(acc_[3]) & 0xFFFFFC00u) | kk_;         \
        bk[rs_][0] = umax(bk[rs_][0], k0_);                                    \
        bk[rs_][1] = umax(bk[rs_][1], k1_);                                    \
        bk[rs_][2] = umax(bk[rs_][2], k2_);                                    \
        bk[rs_][3] = umax(bk[rs_][3], k3_);                                    \
      }                                                                        \
    }                                                                          \
  }

  int cur = 0;
  for (int ks = 0; ks < 16; ++ks) {
    const int tid = (rot + ks) & 15;
    uint4 s0, s1;
    if (ks < 15) {
      // issue next tile's global loads EARLY (latency hides under compute)
      const char* src = (const char*)mbf8 + (((rot + ks + 1) & 15) * TILEB);
      s0 = *(const uint4*)(src + t * 32);
      s1 = *(const uint4*)(src + t * 32 + 16);
    }
    const char* bp = Bs[cur];
    COMPUTE_TILE(tid, bp);
    if (ks < 15) {
      char* dst = Bs[cur ^ 1];
      *(uint4*)(dst + wdst0) = s0;
      *(uint4*)(dst + wdst1) = s1;
    }
    __syncthreads();
    cur ^= 1;
  }
#undef COMPUTE_TILE

  // ---- reduce keys across the 16 column-lanes; extract centroid idx ----
#pragma unroll
  for (int rs = 0; rs < 4; ++rs)
#pragma unroll
    for (int e = 0; e < 4; ++e) {
      unsigned k = bk[rs][e];
#pragma unroll
      for (int m = 1; m < 16; m <<= 1) {
        unsigned o = (unsigned)__shfl_xor((int)k, m, 64);
        k = umax(k, o);
      }
      if (lr == 0) idxs[w * 64 + rs * 16 + lhi * 4 + e] = (int)(k & 1023u);
    }
  __syncthreads();

  // ---- exact fp32 loss for assigned centroids (1 row per thread) ----
  {
    long n = nbase + t;
    int ai = idxs[t];
    const float4* xr = (const float4*)(X + n * D);
    const float4* mr = (const float4*)(means + (long)ai * D);
    float s = 0.f;
#pragma unroll 8
    for (int i = 0; i < 32; ++i) {
      float4 xv = xr[i];
      float4 mv = mr[i];
      float d0 = xv.x - mv.x, d1 = xv.y - mv.y;
      float d2 = xv.z - mv.z, d3 = xv.w - mv.w;
      s = fmaf(d0, d0, s);
      s = fmaf(d1, d1, s);
      s = fmaf(d2, d2, s);
      s = fmaf(d3, d3, s);
    }
#pragma unroll
    for (int m = 32; m; m >>= 1) s += __shfl_down(s, m, 64);
    if (l == 0) wsum[w] = s;
  }
  __syncthreads();
  if (t == 0) partials[blockIdx.x] = wsum[0] + wsum[1] + wsum[2] + wsum[3];
}

// Kernel 3: deterministic fixed-order final reduction (double accum).
__global__ void reduce_loss(const float* __restrict__ partials,
                            float* __restrict__ out) {
  __shared__ double ws[4];
  int t = threadIdx.x;
  double s = 0.0;
  for (int i = t; i < NBLK; i += 256) s += (double)partials[i];
#pragma unroll
  for (int m = 32; m; m >>= 1) s += __shfl_down(s, m, 64);
  if ((t & 63) == 0) ws[t >> 6] = s;
  __syncthreads();
  if (t == 0) out[0] = (float)(ws[0] + ws[1] + ws[2] + ws[3]);
}

extern "C" void kernel_launch(void* const* d_in, const int* in_sizes, int n_in,
                              void* d_out, int out_size, void* d_ws,
                              size_t ws_size, hipStream_t stream) {
  const float* X = (const float*)d_in[0];
  const float* means = (const float*)d_in[1];
  float* out = (float*)d_out;
  char* ws = (char*)d_ws;
  unsigned char* mbf8 = (unsigned char*)ws;         // 131072 B
  float* bigm2 = (float*)(ws + 131072);             // 4096 B
  float* partials = (float*)(ws + 131072 + 4096);   // 4096 B

  prep_means<<<K_TOTAL, 64, 0, stream>>>(means, mbf8, bigm2);
  kmeans_main<<<NBLK, 256, 0, stream>>>(X, mbf8, bigm2, means, partials);
  reduce_loss<<<1, 256, 0, stream>>>(partials, out);
}